// Round 8
// baseline (263.323 us; speedup 1.0000x reference)
//
#include <hip/hip_runtime.h>
#include <hip/hip_cooperative_groups.h>
#include <math.h>

namespace cg = cooperative_groups;

#define B_ 4
#define T_ 336
#define N_ 862
#define D_ 64
#define R_ 8
#define K_ 6
#define P_ 96
#define NR 896   // padded n-stride
#define CAP 32   // CSR cap per row
#define NB 864   // padded 862

// workspace float offsets
#define OFF_PC   0        // 192: PC (96) then PA (96)
#define OFF_XBP  768      // 4*6*864 xbar t-partials
#define OFF_DINV 21504    // 864
#define OFF_WGT  22368    // 6*3456 (j-major: j*3456 + b*864 + n)
#define OFF_IDX  43104    // 6*3456 int
#define OFF_CNT  63840    // 864 int
#define OFF_CSRV 64704    // 32*864 (j-major)
#define OFF_CSRI 92352    // 32*864 int
#define OFF_P12  120000   // 336*192
#define OFF_PCP  184512   // 336*192 per-t partials of PC/PA
#define OFF_XPT  249024   // 4*192*896 = 688128 (end 937152 floats)

__global__ __launch_bounds__(256) void mega(const float* __restrict__ x,
                                            const float* __restrict__ Whead,
                                            const float* __restrict__ A,
                                            const float* __restrict__ We,
                                            const float* __restrict__ be,
                                            const float* __restrict__ W1,
                                            const float* __restrict__ W2,
                                            const float* __restrict__ gate,
                                            const float* __restrict__ Wgcn,
                                            const float* __restrict__ ggcn,
                                            const float* __restrict__ bhead,
                                            float* __restrict__ ws,
                                            float* __restrict__ out) {
  cg::grid_group grid = cg::this_grid();
  __shared__ float smem[9984];
  __shared__ float sW1[64], sW2[64], sCB[64], sWe[64];
  __shared__ float s_sc[4][R_];
  __shared__ float s_scal[5];
  __shared__ float selv[12];
  __shared__ int seli[12];
  int tid = threadIdx.x;
  int bid = blockIdx.x;
  int gsz = gridDim.x;
  float g = 1.f / (1.f + expf(-gate[0]));
  // block-level projection tables (t-independent)
  if (tid < 64) {
    float a = 0.f;
#pragma unroll
    for (int dd = 0; dd < D_; ++dd) a += We[dd] * Wgcn[dd * D_ + tid];
    sW1[tid] = a;
  } else if (tid < 128) {
    int e = tid - 64;
    float a = 0.f;
#pragma unroll
    for (int dd = 0; dd < D_; ++dd) a += be[dd] * Wgcn[dd * D_ + e];
    sW2[e] = (1.f + g) * a;
  } else if (tid < 192) {
    int e = tid - 128;
    sCB[e] = (1.f + g) * be[e];
    sWe[e] = We[e];
  }
  __syncthreads();

  // ================= Phase A: proj(252) + xbar(336) + csr(216) = 804 tasks
  for (int vb = bid; vb < 804; vb += gsz) {
    if (vb < 252) {
      int idx = vb * 256 + tid;          // [0, 64512)
      int t = idx / 192, c = idx % 192;
      int p = c - (c >= P_ ? P_ : 0);
      bool sel = (c >= P_);
      const float* cA = sel ? sW1 : sWe;
      const float* cB = sel ? sW2 : sCB;
      const float* wrow = Whead + (size_t)t * D_ * P_ + p;
      float a = 0.f, bacc = 0.f;
#pragma unroll
      for (int e = 0; e < D_; ++e) {
        float w = wrow[(size_t)e * P_];
        a = fmaf(cA[e], w, a);
        bacc = fmaf(cB[e], w, bacc);
      }
      ws[OFF_P12 + idx] = a;
      ws[OFF_PCP + idx] = bacc;
    } else if (vb < 588) {
      int iq = vb - 252;
      int b = iq / 84, rem = iq % 84;
      int ch = rem / 6, tg = rem % 6;
      int lane = tid & 63, tsub = tid >> 6;
      int n = ch * 64 + lane;
      float s = 0.f;
      if (n < N_) {
        const float* xp = x + (size_t)(b * T_) * N_ + n;
        int tend = tg * 56 + 56;
#pragma unroll 7
        for (int t = tg * 56 + tsub; t < tend; t += 4) s += xp[(size_t)t * N_];
      }
      smem[tid] = s;
      __syncthreads();
      if (tsub == 0 && n < N_)
        ws[OFF_XBP + (size_t)(b * 6 + tg) * NB + n] =
            smem[lane] + smem[64 + lane] + smem[128 + lane] + smem[192 + lane];
      __syncthreads();
    } else {
      // CSR + dinv: 4 rows per task, one per wave
      int lane = tid & 63, wv = tid >> 6;
      int n = (vb - 588) * 4 + wv;
      if (n < N_) {
        const float* ap = A + (size_t)n * N_;
        float* vout = ws + OFF_CSRV;
        int* iout = (int*)(ws + OFF_CSRI);
        float s = 0.f;
        int total = 0;
        for (int base = 0; base < N_; base += 64) {
          int m = base + lane;
          float a = (m < N_) ? ap[m] : 0.f;
          s += a;
          bool nz = (a != 0.f);
          unsigned long long mask = __ballot(nz);
          int pos = __popcll(mask & ((1ull << lane) - 1ull));
          if (nz) {
            int slot = total + pos;
            if (slot < CAP) { vout[slot * NB + n] = a; iout[slot * NB + n] = m; }
          }
          total += __popcll(mask);
        }
        for (int off = 32; off; off >>= 1) s += __shfl_down(s, off);
        if (lane == 0) {
          ws[OFF_DINV + n] = (s > 0.f) ? (1.f / sqrtf(s)) : 0.f;
          ((int*)(ws + OFF_CNT))[n] = (total <= CAP) ? total : -1;
        }
      }
    }
  }
  grid.sync();

  // ================= Phase B: GEMM(432) + topk(4) + PC reduce(1) = 437 tasks
  for (int vb = bid; vb < 437; vb += gsz) {
    if (vb < 432) {
      // GEMM tile: 8n x 192c, BK=48. 256 threads: c0=(tid&63)*3, 2n per thread.
      float* xs = smem;          // 48*8
      float* ps = smem + 384;    // 48*192
      int b = vb / 108;
      int n0 = (vb % 108) * 8;
      int cg_ = tid & 63, ng = tid >> 6;
      int c0 = cg_ * 3;
      const float* P = ws + OFF_P12;
      float a00 = 0.f, a01 = 0.f, a10 = 0.f, a11 = 0.f, a20 = 0.f, a21 = 0.f;
      for (int kc = 0; kc < 7; ++kc) {
        int t0 = kc * 48;
        if (tid < 96) {
          int row = tid >> 1, col4 = (tid & 1) * 4;
          const float* xr = x + (size_t)(b * T_ + t0 + row) * N_;
          if (n0 + 7 < N_) {
            *(float4*)(xs + row * 8 + col4) = *(const float4*)(xr + n0 + col4);
          } else {
            float* dst = xs + row * 8 + col4;
#pragma unroll
            for (int q = 0; q < 4; ++q) {
              int nn = n0 + col4 + q; if (nn > N_ - 1) nn = N_ - 1;
              dst[q] = xr[nn];
            }
          }
        }
#pragma unroll
        for (int sIdx = 0; sIdx < 9; ++sIdx) {
          int i4 = tid + sIdx * 256;
          int row = i4 / 48, col4 = i4 % 48;
          *(float4*)(ps + row * 192 + col4 * 4) =
              *(const float4*)(P + (size_t)(t0 + row) * 192 + col4 * 4);
        }
        __syncthreads();
#pragma unroll 6
        for (int kk = 0; kk < 48; ++kk) {
          float x0 = xs[kk * 8 + ng * 2];
          float x1 = xs[kk * 8 + ng * 2 + 1];
          float p0 = ps[kk * 192 + c0];
          float p1 = ps[kk * 192 + c0 + 1];
          float p2 = ps[kk * 192 + c0 + 2];
          a00 = fmaf(p0, x0, a00); a01 = fmaf(p0, x1, a01);
          a10 = fmaf(p1, x0, a10); a11 = fmaf(p1, x1, a11);
          a20 = fmaf(p2, x0, a20); a21 = fmaf(p2, x1, a21);
        }
        __syncthreads();
      }
      int n = n0 + ng * 2;
      float accs[3][2] = {{a00, a01}, {a10, a11}, {a20, a21}};
#pragma unroll
      for (int cc = 0; cc < 3; ++cc) {
        float* op = ws + OFF_XPT + ((size_t)(b * 192 + c0 + cc)) * NR + n;
        if (n + 1 < N_) { *(float2*)op = *(float2*)accs[cc]; }
        else if (n < N_) { op[0] = accs[cc][0]; }
      }
    } else if (vb < 436) {
      // ---- top-6 / bottom-6 of xbar for batch b, then softmax weights
      float* sx = smem;            // 864
      float* wkmax = smem + 864;   // 864
      float* wkmin = smem + 1728;  // 864
      int b = vb - 432;
      if (tid < 16) {
        int r = tid & 7, which = tid >> 3;
        const float* W = which ? W2 : W1;
        float a = 0.f, bb = 0.f;
        for (int dd = 0; dd < D_; ++dd) {
          float w = W[dd * R_ + r];
          a += We[dd] * w; bb += be[dd] * w;
        }
        s_sc[which * 2][r] = a; s_sc[which * 2 + 1][r] = bb;
      }
      const float invT = 1.f / (float)T_;
      for (int i = tid; i < NB; i += 256) {
        float v = 0.f;
        if (i < N_) {
          const float* xp = ws + OFF_XBP + (size_t)(b * 6) * NB + i;
#pragma unroll
          for (int q = 0; q < 6; ++q) v += xp[q * NB];
          v *= invT;
        }
        sx[i] = v;
        wkmax[i] = (i < N_) ? v : -3.4e38f;
        wkmin[i] = (i < N_) ? v : 3.4e38f;
      }
      __syncthreads();
      if (tid == 0) {
        float s11 = 0.f, s12 = 0.f, s21 = 0.f, s22 = 0.f;
        for (int r = 0; r < R_; ++r) {
          s11 += s_sc[0][r] * s_sc[2][r];
          s12 += s_sc[0][r] * s_sc[3][r];
          s21 += s_sc[1][r] * s_sc[2][r];
          s22 += s_sc[1][r] * s_sc[3][r];
        }
        s_scal[0] = s11; s_scal[1] = s12; s_scal[2] = s21; s_scal[3] = s22;
        s_scal[4] = g;
      }
      if (tid < 64) {
        int lane = tid;
        for (int r = 0; r < K_; ++r) {
          float bv = -3.4e38f; int bi = 0;
          for (int i = lane; i < N_; i += 64) {
            float v = wkmax[i];
            if (v > bv) { bv = v; bi = i; }
          }
          for (int off = 32; off; off >>= 1) {
            float ov = __shfl_down(bv, off);
            int oi = __shfl_down(bi, off);
            if (ov > bv) { bv = ov; bi = oi; }
          }
          bv = __shfl(bv, 0); bi = __shfl(bi, 0);
          if (lane == 0) { selv[r] = bv; seli[r] = bi; wkmax[bi] = -3.4e38f; }
        }
      } else if (tid < 128) {
        int lane = tid - 64;
        for (int r = 0; r < K_; ++r) {
          float bv = 3.4e38f; int bi = 0;
          for (int i = lane; i < N_; i += 64) {
            float v = wkmin[i];
            if (v < bv) { bv = v; bi = i; }
          }
          for (int off = 32; off; off >>= 1) {
            float ov = __shfl_down(bv, off);
            int oi = __shfl_down(bi, off);
            if (ov < bv) { bv = ov; bi = oi; }
          }
          bv = __shfl(bv, 0); bi = __shfl(bi, 0);
          if (lane == 0) { selv[6 + r] = bv; seli[6 + r] = bi; wkmin[bi] = 3.4e38f; }
        }
      }
      __syncthreads();
      float s11 = s_scal[0], s12 = s_scal[1], s21 = s_scal[2], s22 = s_scal[3];
      float gl = s_scal[4];
      const float rsq = 0.3535533906f;
      for (int n = tid; n < N_; n += 256) {
        float xn = sx[n];
        float alpha = (xn * s11 + s21) * rsq;
        float beta  = (xn * s12 + s22) * rsq;
        int base = (alpha >= 0.f) ? 0 : 6;
        float l[K_]; float mx = -3.4e38f;
#pragma unroll
        for (int j = 0; j < K_; ++j) { l[j] = alpha * selv[base + j] + beta; mx = fmaxf(mx, l[j]); }
        float e[K_]; float ss = 0.f;
#pragma unroll
        for (int j = 0; j < K_; ++j) { e[j] = expf(l[j] - mx); ss += e[j]; }
        float sc = gl / ss;
#pragma unroll
        for (int j = 0; j < K_; ++j) {
          ws[OFF_WGT + j * (4 * NB) + b * NB + n] = e[j] * sc;
          ((int*)(ws + OFF_IDX))[j * (4 * NB) + b * NB + n] = seli[base + j];
        }
      }
      __syncthreads();
    } else {
      // PC/PA full column reduce
      if (tid < 192) {
        float s = 0.f;
#pragma unroll 8
        for (int t = 0; t < T_; ++t) s += ws[OFF_PCP + t * 192 + tid];
        ws[OFF_PC + tid] = s;
      }
    }
  }
  grid.sync();

  // ================= Phase C: final assembly, 1536 tasks (c x 4 n-chunks)
  float gg = ggcn[0];
  for (int vb = bid; vb < 1536; vb += gsz) {
    int c = vb >> 2, chunk = vb & 3;
    int n = chunk * 256 + tid;
    if (n >= N_) continue;
    int b = c / P_, p = c % P_;
    const float* Xp1 = ws + OFF_XPT + ((size_t)(b * 192 + p)) * NR;
    const float* Xp2 = ws + OFF_XPT + ((size_t)(b * 192 + P_ + p)) * NR;
    const float* WGTb = ws + OFF_WGT + b * NB;
    const int* IDXb = (const int*)(ws + OFF_IDX) + b * NB;
    float PCp = ws[OFF_PC + p];
    float PAp = ws[OFF_PC + 96 + p];
    float wj[K_]; int ij[K_];
#pragma unroll
    for (int j = 0; j < K_; ++j) {
      wj[j] = WGTb[j * (4 * NB) + n];
      ij[j] = IDXb[j * (4 * NB) + n];
    }
    float acc1 = Xp1[n];
#pragma unroll
    for (int j = 0; j < K_; ++j) acc1 += wj[j] * Xp1[ij[j]];
    int cnt = ((const int*)(ws + OFF_CNT))[n];
    float S = 0.f;
    if (cnt >= 0) {
      const float* vv = ws + OFF_CSRV;
      const int* ii = (const int*)(ws + OFF_CSRI);
      for (int jj = 0; jj < cnt; ++jj) {
        float a = vv[jj * NB + n];
        int m = ii[jj * NB + n];
        float mix2 = Xp2[m];
        if (m == n) {
#pragma unroll
          for (int j = 0; j < K_; ++j) mix2 += wj[j] * Xp2[ij[j]];
        } else {
#pragma unroll
          for (int j = 0; j < K_; ++j)
            mix2 += WGTb[j * (4 * NB) + m] * Xp2[IDXb[j * (4 * NB) + m]];
        }
        S += a * ws[OFF_DINV + m] * (mix2 + PAp);
      }
    } else {
      const float* ar = A + (size_t)n * N_;
      for (int m = 0; m < N_; ++m) {
        float a = ar[m];
        if (a != 0.f) {
          float mix2 = Xp2[m];
#pragma unroll
          for (int j = 0; j < K_; ++j)
            mix2 += WGTb[j * (4 * NB) + m] * Xp2[IDXb[j * (4 * NB) + m]];
          S += a * ws[OFF_DINV + m] * (mix2 + PAp);
        }
      }
    }
    out[(size_t)c * N_ + n] = acc1 + gg * ws[OFF_DINV + n] * S + PCp + bhead[p];
  }
}

extern "C" void kernel_launch(void* const* d_in, const int* in_sizes, int n_in,
                              void* d_out, int out_size, void* d_ws, size_t ws_size,
                              hipStream_t stream) {
  const float* x     = (const float*)d_in[0];
  const float* We    = (const float*)d_in[1];
  const float* be    = (const float*)d_in[2];
  const float* W1    = (const float*)d_in[3];
  const float* W2    = (const float*)d_in[4];
  const float* gate  = (const float*)d_in[5];
  const float* A     = (const float*)d_in[6];
  const float* Wgcn  = (const float*)d_in[7];
  const float* ggcn  = (const float*)d_in[8];
  const float* Whead = (const float*)d_in[9];
  const float* bhead = (const float*)d_in[10];
  float* ws = (float*)d_ws;
  float* out = (float*)d_out;

  // occupancy-sized cooperative grid (queried at capture time; pure host query,
  // no stream ops). 3 blocks/CU expected (41 KB LDS); grid-stride loops in the
  // kernel handle any grid size.
  int occ = 0;
  if (hipOccupancyMaxActiveBlocksPerMultiprocessor(&occ, mega, 256, 0) != hipSuccess || occ < 1)
    occ = 1;
  if (occ > 3) occ = 3;
  int grid = occ * 256;

  void* args[13];
  args[0] = (void*)&x;    args[1] = (void*)&Whead; args[2] = (void*)&A;
  args[3] = (void*)&We;   args[4] = (void*)&be;    args[5] = (void*)&W1;
  args[6] = (void*)&W2;   args[7] = (void*)&gate;  args[8] = (void*)&Wgcn;
  args[9] = (void*)&ggcn; args[10] = (void*)&bhead;
  args[11] = (void*)&ws;  args[12] = (void*)&out;
  hipLaunchCooperativeKernel((const void*)mega, dim3(grid), dim3(256), args, 0, stream);
}

// Round 9
// 115.358 us; speedup vs baseline: 2.2827x; 2.2827x over previous
//
#include <hip/hip_runtime.h>
#include <math.h>

#define B_ 4
#define T_ 336
#define N_ 862
#define D_ 64
#define R_ 8
#define K_ 6
#define P_ 96
#define NR 896   // padded n-stride
#define CAP 32   // CSR cap per row
#define NB 864   // padded 862

// workspace float offsets
#define OFF_PCQ  0        // 4*192 partial PC/PA
#define OFF_XBP  768      // 4*6*864 xbar t-partials
#define OFF_DINV 21504    // 864
#define OFF_WGT  22368    // 6*3456 (j-major: j*3456 + b*864 + n)
#define OFF_IDX  43104    // 6*3456 int
#define OFF_CNT  63840    // 864 int
#define OFF_CSRV 64704    // 32*864 (j-major)
#define OFF_CSRI 92352    // 32*864 int
#define OFF_P12  120000   // 336*192
#define OFF_PCP  184512   // 336*192 per-t partials of PC/PA
#define OFF_XPT  249024   // 4*192*896 = 688128 (end 937152 floats)

// ---------------- Phase A: proj (336) + xbar partials (336) + CSR/dinv (288).
// grid 960 x 192.
__global__ __launch_bounds__(192) void kA_prep(const float* __restrict__ x,
                                               const float* __restrict__ Whead,
                                               const float* __restrict__ A,
                                               const float* __restrict__ We,
                                               const float* __restrict__ be,
                                               const float* __restrict__ gate,
                                               const float* __restrict__ Wgcn,
                                               float* __restrict__ ws) {
  int id = blockIdx.x;
  int tid = threadIdx.x;
  if (id < 336) {
    // ---- projection for t = id: P12[t][c], PCP[t][c]; Whead tile via LDS
    __shared__ float swh[6144];       // 24 KB: Whead[t] as [e][p]
    __shared__ float sW1[64], sW2[64], sCB[64], sWe[64];
    int t = id;
    const float* wbase = Whead + (size_t)t * (D_ * P_);
    // coalesced stage: 1536 float4, 8 per thread
#pragma unroll
    for (int s = 0; s < 8; ++s) {
      int idx4 = s * 192 + tid;
      *(float4*)(swh + idx4 * 4) = *(const float4*)(wbase + idx4 * 4);
    }
    float g = 1.f / (1.f + expf(-gate[0]));
    if (tid < 64) {
      float a = 0.f;
#pragma unroll
      for (int dd = 0; dd < D_; ++dd) a += We[dd] * Wgcn[dd * D_ + tid];
      sW1[tid] = a;
    } else if (tid < 128) {
      int e = tid - 64;
      float a = 0.f;
#pragma unroll
      for (int dd = 0; dd < D_; ++dd) a += be[dd] * Wgcn[dd * D_ + e];
      sW2[e] = (1.f + g) * a;
    } else {
      int e = tid - 128;
      sCB[e] = (1.f + g) * be[e];
      sWe[e] = We[e];
    }
    __syncthreads();
    int c = tid, p = c % P_, sel = c / P_;
    const float* cA = sel ? sW1 : sWe;
    const float* cB = sel ? sW2 : sCB;
    float a = 0.f, bacc = 0.f;
#pragma unroll
    for (int e = 0; e < D_; ++e) {
      float w = swh[e * P_ + p];      // 2-way bank alias (free); cA/cB broadcast
      a = fmaf(cA[e], w, a);
      bacc = fmaf(cB[e], w, bacc);
    }
    ws[OFF_P12 + t * 192 + c] = a;
    ws[OFF_PCP + t * 192 + c] = bacc;
  } else if (id < 672) {
    // ---- xbar t-partials: block = (b, 64-n chunk, t-group of 56)
    __shared__ float part[192];
    int iq = id - 336;
    int b = iq / 84, rem = iq % 84;
    int ch = rem / 6, tg = rem % 6;
    int lane = tid & 63, tsub = tid >> 6;
    int n = ch * 64 + lane;
    float s = 0.f;
    if (n < N_) {
      const float* xp = x + (size_t)(b * T_) * N_ + n;
      int tend = tg * 56 + 56;
#pragma unroll 4
      for (int t = tg * 56 + tsub; t < tend; t += 3) s += xp[(size_t)t * N_];
    }
    part[tid] = s;
    __syncthreads();
    if (tsub == 0 && n < N_)
      ws[OFF_XBP + (size_t)(b * 6 + tg) * NB + n] =
          part[lane] + part[64 + lane] + part[128 + lane];
  } else {
    // ---- CSR + dinv: 3 rows per block, one per wave
    int lane = tid & 63, wv = tid >> 6;
    int n = (id - 672) * 3 + wv;
    if (n >= N_) return;
    const float* ap = A + (size_t)n * N_;
    float* vout = ws + OFF_CSRV;
    int* iout = (int*)(ws + OFF_CSRI);
    float s = 0.f;
    int total = 0;
    for (int base = 0; base < N_; base += 64) {
      int m = base + lane;
      float a = (m < N_) ? ap[m] : 0.f;
      s += a;
      bool nz = (a != 0.f);
      unsigned long long mask = __ballot(nz);
      int pos = __popcll(mask & ((1ull << lane) - 1ull));
      if (nz) {
        int slot = total + pos;
        if (slot < CAP) { vout[slot * NB + n] = a; iout[slot * NB + n] = m; }
      }
      total += __popcll(mask);
    }
    for (int off = 32; off; off >>= 1) s += __shfl_down(s, off);
    if (lane == 0) {
      ws[OFF_DINV + n] = (s > 0.f) ? (1.f / sqrtf(s)) : 0.f;
      ((int*)(ws + OFF_CNT))[n] = (total <= CAP) ? total : -1;
    }
  }
}

// ---------------- Phase B: GEMM (432 x 8n) + topk (4) + PC/PA partials (4).
// grid 440 x 256.
__global__ __launch_bounds__(256) void kM_mid(const float* __restrict__ x,
                                              const float* __restrict__ W1,
                                              const float* __restrict__ W2,
                                              const float* __restrict__ We,
                                              const float* __restrict__ be,
                                              const float* __restrict__ gate,
                                              float* __restrict__ ws) {
  __shared__ float smem[9600];
  int id = blockIdx.x;
  int tid = threadIdx.x;
  if (id < 432) {
    // GEMM tile: 8n x 192c, BK=48. c0=(tid&63)*3, 2n per thread.
    float* xs = smem;          // 48*8
    float* ps = smem + 384;    // 48*192
    int b = id / 108;
    int n0 = (id % 108) * 8;
    int cg_ = tid & 63, ng = tid >> 6;
    int c0 = cg_ * 3;
    const float* P = ws + OFF_P12;
    float a00 = 0.f, a01 = 0.f, a10 = 0.f, a11 = 0.f, a20 = 0.f, a21 = 0.f;
    for (int kc = 0; kc < 7; ++kc) {
      int t0 = kc * 48;
      if (tid < 96) {
        int row = tid >> 1, col4 = (tid & 1) * 4;
        const float* xr = x + (size_t)(b * T_ + t0 + row) * N_;
        if (n0 + 7 < N_) {
          *(float4*)(xs + row * 8 + col4) = *(const float4*)(xr + n0 + col4);
        } else {
          float* dst = xs + row * 8 + col4;
#pragma unroll
          for (int q = 0; q < 4; ++q) {
            int nn = n0 + col4 + q; if (nn > N_ - 1) nn = N_ - 1;
            dst[q] = xr[nn];
          }
        }
      }
#pragma unroll
      for (int sIdx = 0; sIdx < 9; ++sIdx) {
        int i4 = tid + sIdx * 256;
        int row = i4 / 48, col4 = i4 % 48;
        *(float4*)(ps + row * 192 + col4 * 4) =
            *(const float4*)(P + (size_t)(t0 + row) * 192 + col4 * 4);
      }
      __syncthreads();
#pragma unroll 6
      for (int kk = 0; kk < 48; ++kk) {
        float x0 = xs[kk * 8 + ng * 2];
        float x1 = xs[kk * 8 + ng * 2 + 1];
        float p0 = ps[kk * 192 + c0];
        float p1 = ps[kk * 192 + c0 + 1];
        float p2 = ps[kk * 192 + c0 + 2];
        a00 = fmaf(p0, x0, a00); a01 = fmaf(p0, x1, a01);
        a10 = fmaf(p1, x0, a10); a11 = fmaf(p1, x1, a11);
        a20 = fmaf(p2, x0, a20); a21 = fmaf(p2, x1, a21);
      }
      __syncthreads();
    }
    int n = n0 + ng * 2;
    float accs[3][2] = {{a00, a01}, {a10, a11}, {a20, a21}};
#pragma unroll
    for (int cc = 0; cc < 3; ++cc) {
      float* op = ws + OFF_XPT + ((size_t)(b * 192 + c0 + cc)) * NR + n;
      if (n + 1 < N_) { *(float2*)op = *(float2*)accs[cc]; }
      else if (n < N_) { op[0] = accs[cc][0]; }
    }
  } else if (id < 436) {
    // ---- top-6 / bottom-6 of xbar for batch b, then softmax weights
    __shared__ float s_sc[4][R_];
    __shared__ float s_scal[5];
    __shared__ float selv[12];
    __shared__ int seli[12];
    float* sx = smem;            // 864
    float* wkmax = smem + 864;   // 864
    float* wkmin = smem + 1728;  // 864
    int b = id - 432;
    if (tid < 16) {
      int r = tid & 7, which = tid >> 3;
      const float* W = which ? W2 : W1;
      float a = 0.f, bb = 0.f;
      for (int dd = 0; dd < D_; ++dd) {
        float w = W[dd * R_ + r];
        a += We[dd] * w; bb += be[dd] * w;
      }
      s_sc[which * 2][r] = a; s_sc[which * 2 + 1][r] = bb;
    }
    const float invT = 1.f / (float)T_;
    for (int i = tid; i < NB; i += 256) {
      float v = 0.f;
      if (i < N_) {
        const float* xp = ws + OFF_XBP + (size_t)(b * 6) * NB + i;
#pragma unroll
        for (int q = 0; q < 6; ++q) v += xp[q * NB];
        v *= invT;
      }
      sx[i] = v;
      wkmax[i] = (i < N_) ? v : -3.4e38f;
      wkmin[i] = (i < N_) ? v : 3.4e38f;
    }
    __syncthreads();
    if (tid == 0) {
      float s11 = 0.f, s12 = 0.f, s21 = 0.f, s22 = 0.f;
      for (int r = 0; r < R_; ++r) {
        s11 += s_sc[0][r] * s_sc[2][r];
        s12 += s_sc[0][r] * s_sc[3][r];
        s21 += s_sc[1][r] * s_sc[2][r];
        s22 += s_sc[1][r] * s_sc[3][r];
      }
      s_scal[0] = s11; s_scal[1] = s12; s_scal[2] = s21; s_scal[3] = s22;
      s_scal[4] = 1.f / (1.f + expf(-gate[0]));
    }
    if (tid < 64) {
      int lane = tid;
      for (int r = 0; r < K_; ++r) {
        float bv = -3.4e38f; int bi = 0;
        for (int i = lane; i < N_; i += 64) {
          float v = wkmax[i];
          if (v > bv) { bv = v; bi = i; }
        }
        for (int off = 32; off; off >>= 1) {
          float ov = __shfl_down(bv, off);
          int oi = __shfl_down(bi, off);
          if (ov > bv) { bv = ov; bi = oi; }
        }
        bv = __shfl(bv, 0); bi = __shfl(bi, 0);
        if (lane == 0) { selv[r] = bv; seli[r] = bi; wkmax[bi] = -3.4e38f; }
      }
    } else if (tid < 128) {
      int lane = tid - 64;
      for (int r = 0; r < K_; ++r) {
        float bv = 3.4e38f; int bi = 0;
        for (int i = lane; i < N_; i += 64) {
          float v = wkmin[i];
          if (v < bv) { bv = v; bi = i; }
        }
        for (int off = 32; off; off >>= 1) {
          float ov = __shfl_down(bv, off);
          int oi = __shfl_down(bi, off);
          if (ov < bv) { bv = ov; bi = oi; }
        }
        bv = __shfl(bv, 0); bi = __shfl(bi, 0);
        if (lane == 0) { selv[6 + r] = bv; seli[6 + r] = bi; wkmin[bi] = 3.4e38f; }
      }
    }
    __syncthreads();
    float s11 = s_scal[0], s12 = s_scal[1], s21 = s_scal[2], s22 = s_scal[3];
    float g = s_scal[4];
    const float rsq = 0.3535533906f;
    for (int n = tid; n < N_; n += 256) {
      float xn = sx[n];
      float alpha = (xn * s11 + s21) * rsq;
      float beta  = (xn * s12 + s22) * rsq;
      int base = (alpha >= 0.f) ? 0 : 6;
      float l[K_]; float mx = -3.4e38f;
#pragma unroll
      for (int j = 0; j < K_; ++j) { l[j] = alpha * selv[base + j] + beta; mx = fmaxf(mx, l[j]); }
      float e[K_]; float ss = 0.f;
#pragma unroll
      for (int j = 0; j < K_; ++j) { e[j] = expf(l[j] - mx); ss += e[j]; }
      float sc = g / ss;
#pragma unroll
      for (int j = 0; j < K_; ++j) {
        ws[OFF_WGT + j * (4 * NB) + b * NB + n] = e[j] * sc;
        ((int*)(ws + OFF_IDX))[j * (4 * NB) + b * NB + n] = seli[base + j];
      }
    }
  } else {
    // ---- PC/PA partial column reduce: block q sums 84 t's
    int q = id - 436;
    if (tid < 192) {
      float s = 0.f;
#pragma unroll 12
      for (int t = q * 84; t < q * 84 + 84; ++t) s += ws[OFF_PCP + t * 192 + tid];
      ws[OFF_PCQ + q * 192 + tid] = s;
    }
  }
}

// ---------------- Phase C: fused mix1 + on-the-fly GCN + assembly.
// grid(4,384) x 256. blockIdx.y = c = b*96+p.
__global__ __launch_bounds__(256) void kF_final(const float* __restrict__ A,
                                                const float* __restrict__ bhead,
                                                const float* __restrict__ ggcn,
                                                const float* __restrict__ ws,
                                                float* __restrict__ out) {
  int c = blockIdx.y;
  int n = blockIdx.x * 256 + threadIdx.x;
  if (n >= N_) return;
  int b = c / P_, p = c % P_;
  const float* Xp1 = ws + OFF_XPT + ((size_t)(b * 192 + p)) * NR;
  const float* Xp2 = ws + OFF_XPT + ((size_t)(b * 192 + P_ + p)) * NR;
  const float* WGTb = ws + OFF_WGT + b * NB;
  const int* IDXb = (const int*)(ws + OFF_IDX) + b * NB;
  float gg = ggcn[0];
  float PCp = 0.f, PAp = 0.f;
#pragma unroll
  for (int q = 0; q < 4; ++q) {
    PCp += ws[OFF_PCQ + q * 192 + p];
    PAp += ws[OFF_PCQ + q * 192 + 96 + p];
  }
  float wj[K_]; int ij[K_];
#pragma unroll
  for (int j = 0; j < K_; ++j) {
    wj[j] = WGTb[j * (4 * NB) + n];
    ij[j] = IDXb[j * (4 * NB) + n];
  }
  float acc1 = Xp1[n];
#pragma unroll
  for (int j = 0; j < K_; ++j) acc1 += wj[j] * Xp1[ij[j]];
  int cnt = ((const int*)(ws + OFF_CNT))[n];
  float S = 0.f;
  if (cnt >= 0) {
    const float* vv = ws + OFF_CSRV;
    const int* ii = (const int*)(ws + OFF_CSRI);
    for (int jj = 0; jj < cnt; ++jj) {
      float a = vv[jj * NB + n];
      int m = ii[jj * NB + n];
      float mix2 = Xp2[m];
      if (m == n) {
#pragma unroll
        for (int j = 0; j < K_; ++j) mix2 += wj[j] * Xp2[ij[j]];
      } else {
#pragma unroll
        for (int j = 0; j < K_; ++j)
          mix2 += WGTb[j * (4 * NB) + m] * Xp2[IDXb[j * (4 * NB) + m]];
      }
      S += a * ws[OFF_DINV + m] * (mix2 + PAp);
    }
  } else {
    const float* ar = A + (size_t)n * N_;
    for (int m = 0; m < N_; ++m) {
      float a = ar[m];
      if (a != 0.f) {
        float mix2 = Xp2[m];
#pragma unroll
        for (int j = 0; j < K_; ++j)
          mix2 += WGTb[j * (4 * NB) + m] * Xp2[IDXb[j * (4 * NB) + m]];
        S += a * ws[OFF_DINV + m] * (mix2 + PAp);
      }
    }
  }
  out[(size_t)c * N_ + n] = acc1 + gg * ws[OFF_DINV + n] * S + PCp + bhead[p];
}

extern "C" void kernel_launch(void* const* d_in, const int* in_sizes, int n_in,
                              void* d_out, int out_size, void* d_ws, size_t ws_size,
                              hipStream_t stream) {
  const float* x     = (const float*)d_in[0];
  const float* We    = (const float*)d_in[1];
  const float* be    = (const float*)d_in[2];
  const float* W1    = (const float*)d_in[3];
  const float* W2    = (const float*)d_in[4];
  const float* gate  = (const float*)d_in[5];
  const float* A     = (const float*)d_in[6];
  const float* Wgcn  = (const float*)d_in[7];
  const float* ggcn  = (const float*)d_in[8];
  const float* Whead = (const float*)d_in[9];
  const float* bhead = (const float*)d_in[10];
  float* ws = (float*)d_ws;
  float* out = (float*)d_out;

  kA_prep<<<960, 192, 0, stream>>>(x, Whead, A, We, be, gate, Wgcn, ws);
  kM_mid<<<440, 256, 0, stream>>>(x, W1, W2, We, be, gate, ws);
  kF_final<<<dim3(4, 384), 256, 0, stream>>>(A, bhead, ggcn, ws, out);
}

// Round 10
// 109.416 us; speedup vs baseline: 2.4066x; 1.0543x over previous
//
#include <hip/hip_runtime.h>
#include <math.h>

#define B_ 4
#define T_ 336
#define N_ 862
#define D_ 64
#define R_ 8
#define K_ 6
#define P_ 96
#define NR 896   // padded n-stride
#define CAP 32   // CSR cap per row
#define NB 864   // padded 862

// workspace float offsets
#define OFF_PCQ  0        // 4*192 partial PC/PA
#define OFF_XBP  768      // 4*6*864 xbar t-partials
#define OFF_DINV 21504    // 864
#define OFF_WGT  22368    // 6*3456 (j-major: j*3456 + b*864 + n)
#define OFF_IDX  43104    // 6*3456 int
#define OFF_CNT  63840    // 864 int
#define OFF_CSRV 64704    // 32*864 (j-major)
#define OFF_CSRI 92352    // 32*864 int
#define OFF_P12  120000   // 336*192
#define OFF_PCP  184512   // 336*192 per-t partials of PC/PA
#define OFF_XPT  249024   // 4*192*896 = 688128 (end 937152 floats)

// ---------------- Phase A: proj (336) + xbar partials (336) + CSR/dinv (288).
// grid 960 x 192.  (R6 version — per-instruction coalescing already optimal.)
__global__ __launch_bounds__(192) void kA_prep(const float* __restrict__ x,
                                               const float* __restrict__ Whead,
                                               const float* __restrict__ A,
                                               const float* __restrict__ We,
                                               const float* __restrict__ be,
                                               const float* __restrict__ gate,
                                               const float* __restrict__ Wgcn,
                                               float* __restrict__ ws) {
  int id = blockIdx.x;
  int tid = threadIdx.x;
  if (id < 336) {
    // ---- projection for t = id: P12[t][c], PCP[t][c]
    __shared__ float sW1[64], sW2[64], sCB[64], sWe[64];
    int t = id;
    float g = 1.f / (1.f + expf(-gate[0]));
    if (tid < 64) {
      float a = 0.f;
#pragma unroll
      for (int dd = 0; dd < D_; ++dd) a += We[dd] * Wgcn[dd * D_ + tid];
      sW1[tid] = a;
    } else if (tid < 128) {
      int e = tid - 64;
      float a = 0.f;
#pragma unroll
      for (int dd = 0; dd < D_; ++dd) a += be[dd] * Wgcn[dd * D_ + e];
      sW2[e] = (1.f + g) * a;
    } else {
      int e = tid - 128;
      sCB[e] = (1.f + g) * be[e];
      sWe[e] = We[e];
    }
    __syncthreads();
    int c = tid, p = c % P_, sel = c / P_;
    const float* cA = sel ? sW1 : sWe;
    const float* cB = sel ? sW2 : sCB;
    const float* wrow = Whead + (size_t)t * D_ * P_ + p;
    float a = 0.f, bacc = 0.f;
#pragma unroll
    for (int e = 0; e < D_; ++e) {
      float w = wrow[(size_t)e * P_];
      a = fmaf(cA[e], w, a);
      bacc = fmaf(cB[e], w, bacc);
    }
    ws[OFF_P12 + t * 192 + c] = a;
    ws[OFF_PCP + t * 192 + c] = bacc;
  } else if (id < 672) {
    // ---- xbar t-partials: block = (b, 64-n chunk, t-group of 56)
    __shared__ float part[192];
    int iq = id - 336;
    int b = iq / 84, rem = iq % 84;
    int ch = rem / 6, tg = rem % 6;
    int lane = tid & 63, tsub = tid >> 6;
    int n = ch * 64 + lane;
    float s = 0.f;
    if (n < N_) {
      const float* xp = x + (size_t)(b * T_) * N_ + n;
      int tend = tg * 56 + 56;
#pragma unroll 4
      for (int t = tg * 56 + tsub; t < tend; t += 3) s += xp[(size_t)t * N_];
    }
    part[tid] = s;
    __syncthreads();
    if (tsub == 0 && n < N_)
      ws[OFF_XBP + (size_t)(b * 6 + tg) * NB + n] =
          part[lane] + part[64 + lane] + part[128 + lane];
  } else {
    // ---- CSR + dinv: 3 rows per block, one per wave
    int lane = tid & 63, wv = tid >> 6;
    int n = (id - 672) * 3 + wv;
    if (n >= N_) return;
    const float* ap = A + (size_t)n * N_;
    float* vout = ws + OFF_CSRV;
    int* iout = (int*)(ws + OFF_CSRI);
    float s = 0.f;
    int total = 0;
    for (int base = 0; base < N_; base += 64) {
      int m = base + lane;
      float a = (m < N_) ? ap[m] : 0.f;
      s += a;
      bool nz = (a != 0.f);
      unsigned long long mask = __ballot(nz);
      int pos = __popcll(mask & ((1ull << lane) - 1ull));
      if (nz) {
        int slot = total + pos;
        if (slot < CAP) { vout[slot * NB + n] = a; iout[slot * NB + n] = m; }
      }
      total += __popcll(mask);
    }
    for (int off = 32; off; off >>= 1) s += __shfl_down(s, off);
    if (lane == 0) {
      ws[OFF_DINV + n] = (s > 0.f) ? (1.f / sqrtf(s)) : 0.f;
      ((int*)(ws + OFF_CNT))[n] = (total <= CAP) ? total : -1;
    }
  }
}

// ---------------- Phase B: GEMM (432: 16n x 96c) + topk (4) + PC/PA partials (4).
// grid 440 x 192.
__global__ __launch_bounds__(192) void kM_mid(const float* __restrict__ x,
                                              const float* __restrict__ W1,
                                              const float* __restrict__ W2,
                                              const float* __restrict__ We,
                                              const float* __restrict__ be,
                                              const float* __restrict__ gate,
                                              float* __restrict__ ws) {
  __shared__ float smem[5376];   // GEMM: xs 768 + ps 4608 = 21.5 KB
  int id = blockIdx.x;
  int tid = threadIdx.x;
  if (id < 432) {
    // GEMM tile: 16n x 96c, BK=48. thread: cq=tid%24 (4c), nq=tid/24 (2n).
    float* xs = smem;          // 48*16
    float* ps = smem + 768;    // 48*96
    int b = id / 108;
    int rem = id % 108;
    int n0 = (rem >> 1) * 16;
    int ch = (rem & 1) * 96;   // c-half offset
    int cq = tid % 24, nq = tid / 24;   // nq in [0,8)
    int c0 = cq * 4;
    const float* P = ws + OFF_P12;
    float acc[4][2];
#pragma unroll
    for (int i = 0; i < 4; ++i) { acc[i][0] = 0.f; acc[i][1] = 0.f; }
    int xrow = tid >> 2, xcol4 = tid & 3;
    for (int kc = 0; kc < 7; ++kc) {
      int t0 = kc * 48;
      {
        const float* xr = x + (size_t)(b * T_ + t0 + xrow) * N_;
        if (n0 + 15 < N_) {
          *(float4*)(xs + xrow * 16 + xcol4 * 4) = *(const float4*)(xr + n0 + xcol4 * 4);
        } else {
          float* dst = xs + xrow * 16 + xcol4 * 4;
#pragma unroll
          for (int q = 0; q < 4; ++q) {
            int nn = n0 + xcol4 * 4 + q; if (nn > N_ - 1) nn = N_ - 1;
            dst[q] = xr[nn];
          }
        }
      }
#pragma unroll
      for (int sIdx = 0; sIdx < 6; ++sIdx) {
        int i4 = tid + sIdx * 192;
        int row = i4 / 24, col4 = i4 % 24;
        *(float4*)(ps + row * 96 + col4 * 4) =
            *(const float4*)(P + (size_t)(t0 + row) * 192 + ch + col4 * 4);
      }
      __syncthreads();
#pragma unroll 6
      for (int kk = 0; kk < 48; ++kk) {
        float x0 = xs[kk * 16 + nq * 2];
        float x1 = xs[kk * 16 + nq * 2 + 1];
        float4 pv = *(const float4*)(ps + kk * 96 + c0);
        acc[0][0] = fmaf(pv.x, x0, acc[0][0]); acc[0][1] = fmaf(pv.x, x1, acc[0][1]);
        acc[1][0] = fmaf(pv.y, x0, acc[1][0]); acc[1][1] = fmaf(pv.y, x1, acc[1][1]);
        acc[2][0] = fmaf(pv.z, x0, acc[2][0]); acc[2][1] = fmaf(pv.z, x1, acc[2][1]);
        acc[3][0] = fmaf(pv.w, x0, acc[3][0]); acc[3][1] = fmaf(pv.w, x1, acc[3][1]);
      }
      __syncthreads();
    }
    int n = n0 + nq * 2;
#pragma unroll
    for (int cc = 0; cc < 4; ++cc) {
      float* op = ws + OFF_XPT + ((size_t)(b * 192 + ch + c0 + cc)) * NR + n;
      if (n + 1 < N_) { float2 v; v.x = acc[cc][0]; v.y = acc[cc][1]; *(float2*)op = v; }
      else if (n < N_) { op[0] = acc[cc][0]; }
    }
  } else if (id < 436) {
    // ---- top-6 / bottom-6 of xbar for batch b, then softmax weights
    __shared__ float s_sc[4][R_];
    __shared__ float s_scal[5];
    __shared__ float selv[12];
    __shared__ int seli[12];
    float* sx = smem;            // 864
    float* wkmax = smem + 864;   // 864
    float* wkmin = smem + 1728;  // 864
    int b = id - 432;
    if (tid < 16) {
      int r = tid & 7, which = tid >> 3;
      const float* W = which ? W2 : W1;
      float a = 0.f, bb = 0.f;
      for (int dd = 0; dd < D_; ++dd) {
        float w = W[dd * R_ + r];
        a += We[dd] * w; bb += be[dd] * w;
      }
      s_sc[which * 2][r] = a; s_sc[which * 2 + 1][r] = bb;
    }
    const float invT = 1.f / (float)T_;
    for (int i = tid; i < NB; i += 192) {
      float v = 0.f;
      if (i < N_) {
        const float* xp = ws + OFF_XBP + (size_t)(b * 6) * NB + i;
#pragma unroll
        for (int q = 0; q < 6; ++q) v += xp[q * NB];
        v *= invT;
      }
      sx[i] = v;
      wkmax[i] = (i < N_) ? v : -3.4e38f;
      wkmin[i] = (i < N_) ? v : 3.4e38f;
    }
    __syncthreads();
    if (tid == 0) {
      float s11 = 0.f, s12 = 0.f, s21 = 0.f, s22 = 0.f;
      for (int r = 0; r < R_; ++r) {
        s11 += s_sc[0][r] * s_sc[2][r];
        s12 += s_sc[0][r] * s_sc[3][r];
        s21 += s_sc[1][r] * s_sc[2][r];
        s22 += s_sc[1][r] * s_sc[3][r];
      }
      s_scal[0] = s11; s_scal[1] = s12; s_scal[2] = s21; s_scal[3] = s22;
      s_scal[4] = 1.f / (1.f + expf(-gate[0]));
    }
    if (tid < 64) {
      int lane = tid;
      for (int r = 0; r < K_; ++r) {
        float bv = -3.4e38f; int bi = 0;
        for (int i = lane; i < N_; i += 64) {
          float v = wkmax[i];
          if (v > bv) { bv = v; bi = i; }
        }
        for (int off = 32; off; off >>= 1) {
          float ov = __shfl_down(bv, off);
          int oi = __shfl_down(bi, off);
          if (ov > bv) { bv = ov; bi = oi; }
        }
        bv = __shfl(bv, 0); bi = __shfl(bi, 0);
        if (lane == 0) { selv[r] = bv; seli[r] = bi; wkmax[bi] = -3.4e38f; }
      }
    } else if (tid < 128) {
      int lane = tid - 64;
      for (int r = 0; r < K_; ++r) {
        float bv = 3.4e38f; int bi = 0;
        for (int i = lane; i < N_; i += 64) {
          float v = wkmin[i];
          if (v < bv) { bv = v; bi = i; }
        }
        for (int off = 32; off; off >>= 1) {
          float ov = __shfl_down(bv, off);
          int oi = __shfl_down(bi, off);
          if (ov < bv) { bv = ov; bi = oi; }
        }
        bv = __shfl(bv, 0); bi = __shfl(bi, 0);
        if (lane == 0) { selv[6 + r] = bv; seli[6 + r] = bi; wkmin[bi] = 3.4e38f; }
      }
    }
    __syncthreads();
    float s11 = s_scal[0], s12 = s_scal[1], s21 = s_scal[2], s22 = s_scal[3];
    float g = s_scal[4];
    const float rsq = 0.3535533906f;
    for (int n = tid; n < N_; n += 192) {
      float xn = sx[n];
      float alpha = (xn * s11 + s21) * rsq;
      float beta  = (xn * s12 + s22) * rsq;
      int base = (alpha >= 0.f) ? 0 : 6;
      float l[K_]; float mx = -3.4e38f;
#pragma unroll
      for (int j = 0; j < K_; ++j) { l[j] = alpha * selv[base + j] + beta; mx = fmaxf(mx, l[j]); }
      float e[K_]; float ss = 0.f;
#pragma unroll
      for (int j = 0; j < K_; ++j) { e[j] = expf(l[j] - mx); ss += e[j]; }
      float sc = g / ss;
#pragma unroll
      for (int j = 0; j < K_; ++j) {
        ws[OFF_WGT + j * (4 * NB) + b * NB + n] = e[j] * sc;
        ((int*)(ws + OFF_IDX))[j * (4 * NB) + b * NB + n] = seli[base + j];
      }
    }
  } else {
    // ---- PC/PA partial column reduce: block q sums 84 t's
    int q = id - 436;
    if (tid < 192) {
      float s = 0.f;
#pragma unroll 12
      for (int t = q * 84; t < q * 84 + 84; ++t) s += ws[OFF_PCP + t * 192 + tid];
      ws[OFF_PCQ + q * 192 + tid] = s;
    }
  }
}

// ---------------- Phase C: fused mix1 + on-the-fly GCN + assembly.
// grid(4,384) x 256. blockIdx.y = c = b*96+p.
__global__ __launch_bounds__(256) void kF_final(const float* __restrict__ A,
                                                const float* __restrict__ bhead,
                                                const float* __restrict__ ggcn,
                                                const float* __restrict__ ws,
                                                float* __restrict__ out) {
  int c = blockIdx.y;
  int n = blockIdx.x * 256 + threadIdx.x;
  if (n >= N_) return;
  int b = c / P_, p = c % P_;
  const float* Xp1 = ws + OFF_XPT + ((size_t)(b * 192 + p)) * NR;
  const float* Xp2 = ws + OFF_XPT + ((size_t)(b * 192 + P_ + p)) * NR;
  const float* WGTb = ws + OFF_WGT + b * NB;
  const int* IDXb = (const int*)(ws + OFF_IDX) + b * NB;
  float gg = ggcn[0];
  float PCp = 0.f, PAp = 0.f;
#pragma unroll
  for (int q = 0; q < 4; ++q) {
    PCp += ws[OFF_PCQ + q * 192 + p];
    PAp += ws[OFF_PCQ + q * 192 + 96 + p];
  }
  float wj[K_]; int ij[K_];
#pragma unroll
  for (int j = 0; j < K_; ++j) {
    wj[j] = WGTb[j * (4 * NB) + n];
    ij[j] = IDXb[j * (4 * NB) + n];
  }
  float acc1 = Xp1[n];
#pragma unroll
  for (int j = 0; j < K_; ++j) acc1 += wj[j] * Xp1[ij[j]];
  int cnt = ((const int*)(ws + OFF_CNT))[n];
  float S = 0.f;
  if (cnt >= 0) {
    const float* vv = ws + OFF_CSRV;
    const int* ii = (const int*)(ws + OFF_CSRI);
    for (int jj = 0; jj < cnt; ++jj) {
      float a = vv[jj * NB + n];
      int m = ii[jj * NB + n];
      float mix2 = Xp2[m];
      if (m == n) {
#pragma unroll
        for (int j = 0; j < K_; ++j) mix2 += wj[j] * Xp2[ij[j]];
      } else {
#pragma unroll
        for (int j = 0; j < K_; ++j)
          mix2 += WGTb[j * (4 * NB) + m] * Xp2[IDXb[j * (4 * NB) + m]];
      }
      S += a * ws[OFF_DINV + m] * (mix2 + PAp);
    }
  } else {
    const float* ar = A + (size_t)n * N_;
    for (int m = 0; m < N_; ++m) {
      float a = ar[m];
      if (a != 0.f) {
        float mix2 = Xp2[m];
#pragma unroll
        for (int j = 0; j < K_; ++j)
          mix2 += WGTb[j * (4 * NB) + m] * Xp2[IDXb[j * (4 * NB) + m]];
        S += a * ws[OFF_DINV + m] * (mix2 + PAp);
      }
    }
  }
  out[(size_t)c * N_ + n] = acc1 + gg * ws[OFF_DINV + n] * S + PCp + bhead[p];
}

extern "C" void kernel_launch(void* const* d_in, const int* in_sizes, int n_in,
                              void* d_out, int out_size, void* d_ws, size_t ws_size,
                              hipStream_t stream) {
  const float* x     = (const float*)d_in[0];
  const float* We    = (const float*)d_in[1];
  const float* be    = (const float*)d_in[2];
  const float* W1    = (const float*)d_in[3];
  const float* W2    = (const float*)d_in[4];
  const float* gate  = (const float*)d_in[5];
  const float* A     = (const float*)d_in[6];
  const float* Wgcn  = (const float*)d_in[7];
  const float* ggcn  = (const float*)d_in[8];
  const float* Whead = (const float*)d_in[9];
  const float* bhead = (const float*)d_in[10];
  float* ws = (float*)d_ws;
  float* out = (float*)d_out;

  kA_prep<<<960, 192, 0, stream>>>(x, Whead, A, We, be, gate, Wgcn, ws);
  kM_mid<<<440, 192, 0, stream>>>(x, W1, W2, We, be, gate, ws);
  kF_final<<<dim3(4, 384), 256, 0, stream>>>(A, bhead, ggcn, ws, out);
}